// Round 6
// baseline (242.107 us; speedup 1.0000x reference)
//
#include <hip/hip_runtime.h>
#include <math.h>

#define B_   2
#define C_   256
#define H_   200
#define W_   272
#define HW_  (H_*W_)
#define NBIN 49
#define SCALE 0.0625f

// ---------------------------------------------------------------------------
// bf16 helpers (staging buffer only; all arithmetic stays f32)
// ---------------------------------------------------------------------------
__device__ __forceinline__ unsigned short f2bf(float f) {
    union { float f; unsigned int i; } v; v.f = f;
    unsigned int x = v.i;
    return (unsigned short)((x + 0x7FFFu + ((x >> 16) & 1u)) >> 16);   // RNE
}
__device__ __forceinline__ float bf2f(unsigned int u16) {
    union { unsigned int i; float f; } v; v.i = u16 << 16; return v.f;
}

// ---------------------------------------------------------------------------
// Geometry: bit-exact vs numpy f32 reference (verified: absmax 0.0 in R1).
// DO NOT TOUCH: fp contract off, same association order, f64 trig.
// ---------------------------------------------------------------------------
__device__ __forceinline__ float edge_mask(float yy, float xx) {
    return (yy > -1.0f && yy < (float)H_ && xx > -1.0f && xx < (float)W_) ? 1.0f : 0.0f;
}

__device__ void compute_geom(const float* __restrict__ rois, int r, int bin,
                             int& b, int& yt, int& yb, int& xl, int& xr,
                             float w[4]) {
#pragma clang fp contract(off)
    const float* rp = rois + r * 6;
    b = (int)rp[0];
    float cx = rp[1] * SCALE;
    float cy = rp[2] * SCALE;
    float rw = rp[3] * SCALE;
    float rh = rp[4] * SCALE;
    float theta = rp[5] * (float)(M_PI / 180.0);
    float Sx = rw / 7.0f;
    float Sy = rh / 7.0f;
    double th = (double)theta;
    float ca = (float)cos(th);
    float sa = (float)sin(th);

    float M00 = ca * Sx;
    float M01 = sa * Sy;
    float M02 = (M00 * (-3.5f) + M01 * (-3.5f)) + cx;
    float M10 = (-sa) * Sx;
    float M11 = ca * Sy;
    float M12 = (M10 * (-3.5f) + M11 * (-3.5f)) + cy;

    float pwf = (float)(bin % 7);
    float phf = (float)(bin / 7);
    float x0 = pwf, x1 = pwf + 1.0f;
    float y0 = phf, y1 = phf + 1.0f;

    float X00 = (M00 * x0 + M01 * y0) + M02;
    float X01 = (M00 * x0 + M01 * y1) + M02;
    float X10 = (M00 * x1 + M01 * y0) + M02;
    float X11 = (M00 * x1 + M01 * y1) + M02;
    float Y00 = (M10 * x0 + M11 * y0) + M12;
    float Y01 = (M10 * x0 + M11 * y1) + M12;
    float Y10 = (M10 * x1 + M11 * y0) + M12;
    float Y11 = (M10 * x1 + M11 * y1) + M12;

    float minX = fminf(fminf(X00, X01), fminf(X10, X11));
    float maxX = fmaxf(fmaxf(X00, X01), fmaxf(X10, X11));
    float minY = fminf(fminf(Y00, Y01), fminf(Y10, Y11));
    float maxY = fmaxf(fmaxf(Y00, Y01), fmaxf(Y10, Y11));

    float leftMost   = fmaxf(floorf(minX + 0.5f), 0.0f);
    float rightMost  = fminf(floorf(maxX + 0.5f), (float)(W_ - 1));
    float topMost    = fmaxf(floorf(minY + 0.5f), 0.0f);
    float bottomMost = fminf(floorf(maxY + 0.5f), (float)(H_ - 1));

    float bcx = (leftMost + rightMost) * 0.5f;
    float bcy = (topMost + bottomMost) * 0.5f;
    float fl = floorf(bcx), fr = ceilf(bcx);
    float ft = floorf(bcy), fb = ceilf(bcy);
    float rx = bcx - fl;
    float ry = bcy - ft;

    float wlt = (1.0f - rx) * (1.0f - ry);
    float wrt = rx * (1.0f - ry);
    float wrb = rx * ry;
    float wlb = (1.0f - rx) * ry;

    w[0] = wlt * edge_mask(ft, fl);
    w[1] = wrt * edge_mask(ft, fr);
    w[2] = wlb * edge_mask(fb, fl);
    w[3] = wrb * edge_mask(fb, fr);

    yt = min(max((int)ft, 0), H_ - 1);
    yb = min(max((int)fb, 0), H_ - 1);
    xl = min(max((int)fl, 0), W_ - 1);
    xr = min(max((int)fr, 0), W_ - 1);
}

// ---------------------------------------------------------------------------
// R2-proven transpose tile body (64x64, f32 LDS [64][65])
// ---------------------------------------------------------------------------
__device__ __forceinline__ void transpose_tile(const float* __restrict__ in,
                                               unsigned short* __restrict__ outp,
                                               int b, int p0, int c0, int t,
                                               float (*tile)[65]) {
    const float*    ib = in   + (size_t)b * C_ * HW_;
    unsigned short* ob = outp + (size_t)b * HW_ * C_;
    {
        int col4 = t & 15;             // which float4 along pixels
        int row  = t >> 4;             // channel row 0..15
        #pragma unroll
        for (int k = 0; k < 4; k++) {
            int c = row + k * 16;
            float4 v = *(const float4*)(ib + (size_t)(c0 + c) * HW_ + p0 + col4 * 4);
            int p = col4 * 4;
            tile[p + 0][c] = v.x;
            tile[p + 1][c] = v.y;
            tile[p + 2][c] = v.z;
            tile[p + 3][c] = v.w;
        }
    }
    __syncthreads();
    {
        int c8 = t & 7;                // which 8-channel group (16 B bf16)
        int pr = t >> 3;               // pixel row 0..31
        #pragma unroll
        for (int k = 0; k < 2; k++) {
            int p = pr + k * 32;
            ushort4 lo, hi;
            const float* tp = &tile[p][c8 * 8];
            lo.x = f2bf(tp[0]); lo.y = f2bf(tp[1]); lo.z = f2bf(tp[2]); lo.w = f2bf(tp[3]);
            hi.x = f2bf(tp[4]); hi.y = f2bf(tp[5]); hi.z = f2bf(tp[6]); hi.w = f2bf(tp[7]);
            unsigned short* dst = ob + (size_t)(p0 + p) * C_ + c0 + c8 * 8;
            *(ushort4*)(dst)     = lo;
            *(ushort4*)(dst + 4) = hi;
        }
    }
}

__global__ __launch_bounds__(256) void transpose_bf16(const float* __restrict__ in,
                                                      unsigned short* __restrict__ outp) {
    __shared__ float tile[64][65];
    transpose_tile(in, outp, blockIdx.z, blockIdx.x * 64, blockIdx.y * 64,
                   threadIdx.x, tile);
}

// PROBE: 4 tiles per block in one dispatch -> dur ~ 4T, visible in rocprof
__global__ __launch_bounds__(256) void probe_transpose4(const float* __restrict__ in,
                                                        unsigned short* __restrict__ outp) {
    __shared__ float tile[64][65];
    #pragma unroll 1
    for (int rep = 0; rep < 4; rep++) {
        int id   = (blockIdx.x + rep * 1700) % 6800;     // 850*4*2 tiles
        int px   = id % 850;
        int rest = id / 850;
        int cy   = rest % 4;
        int b    = rest / 4;
        transpose_tile(in, outp, b, px * 64, cy * 64, threadIdx.x, tile);
        __syncthreads();
    }
}

// ---------------------------------------------------------------------------
// R2-proven main body: one roi per call; f32 LDS out-stage, uint2 gathers
// ---------------------------------------------------------------------------
__device__ __forceinline__ void main_roi(const unsigned short* __restrict__ xt,
                                         const float* __restrict__ rois,
                                         float* __restrict__ obase, int r, int tid,
                                         float* lout, int (*goff)[4], float (*gw)[4]) {
    if (tid < NBIN) {
        int b, yt, yb, xl, xr; float w[4];
        compute_geom(rois, r, tid, b, yt, yb, xl, xr, w);
        int base = b * HW_ * C_;
        goff[tid][0] = base + (yt * W_ + xl) * C_;
        goff[tid][1] = base + (yt * W_ + xr) * C_;
        goff[tid][2] = base + (yb * W_ + xl) * C_;
        goff[tid][3] = base + (yb * W_ + xr) * C_;
        gw[tid][0] = w[0]; gw[tid][1] = w[1]; gw[tid][2] = w[2]; gw[tid][3] = w[3];
    }
    __syncthreads();

    int lane = tid & 63;
    int wv   = tid >> 6;
    int c4   = lane * 4;

    for (int bin0 = 0; bin0 < NBIN; bin0 += 4) {
        int bin = bin0 + wv;
        if (bin < NBIN) {
            float w0 = gw[bin][0], w1 = gw[bin][1], w2 = gw[bin][2], w3 = gw[bin][3];
            uint2 lt = *(const uint2*)(xt + goff[bin][0] + c4);
            uint2 rt = *(const uint2*)(xt + goff[bin][1] + c4);
            uint2 lb = *(const uint2*)(xt + goff[bin][2] + c4);
            uint2 rb = *(const uint2*)(xt + goff[bin][3] + c4);
            float acc[4];
            {
#pragma clang fp contract(off)
                float a0 = bf2f(lt.x & 0xFFFFu), a1 = bf2f(lt.x >> 16),
                      a2 = bf2f(lt.y & 0xFFFFu), a3 = bf2f(lt.y >> 16);
                float b0 = bf2f(rt.x & 0xFFFFu), b1 = bf2f(rt.x >> 16),
                      b2 = bf2f(rt.y & 0xFFFFu), b3 = bf2f(rt.y >> 16);
                float c0v = bf2f(lb.x & 0xFFFFu), c1v = bf2f(lb.x >> 16),
                      c2v = bf2f(lb.y & 0xFFFFu), c3v = bf2f(lb.y >> 16);
                float d0 = bf2f(rb.x & 0xFFFFu), d1 = bf2f(rb.x >> 16),
                      d2 = bf2f(rb.y & 0xFFFFu), d3 = bf2f(rb.y >> 16);
                acc[0] = ((w0 * a0 + w1 * b0) + w3 * d0) + w2 * c0v;
                acc[1] = ((w0 * a1 + w1 * b1) + w3 * d1) + w2 * c1v;
                acc[2] = ((w0 * a2 + w1 * b2) + w3 * d2) + w2 * c2v;
                acc[3] = ((w0 * a3 + w1 * b3) + w3 * d3) + w2 * c3v;
            }
            #pragma unroll
            for (int jj = 0; jj < 4; jj++) {
                int j = (jj + (lane >> 3)) & 3;   // swizzle: <=2 lanes/bank
                float v = (j == 0) ? acc[0] : (j == 1) ? acc[1] : (j == 2) ? acc[2] : acc[3];
                lout[(c4 + j) * NBIN + bin] = v;
            }
        }
    }
    __syncthreads();

    float4*       o4 = (float4*)obase;
    const float4* l4 = (const float4*)lout;
    const int n4 = (C_ * NBIN) / 4;            // 3136
    for (int i = tid; i < n4; i += 256) o4[i] = l4[i];
}

__global__ __launch_bounds__(256) void rroi_main_bf16(const unsigned short* __restrict__ xt,
                                                      const float* __restrict__ rois,
                                                      float* __restrict__ outp) {
    __shared__ float lout[C_ * NBIN];
    __shared__ int   goff[NBIN][4];
    __shared__ float gw[NBIN][4];
    main_roi(xt, rois, outp + (size_t)blockIdx.x * (C_ * NBIN),
             blockIdx.x, threadIdx.x, lout, goff, gw);
}

// PROBE: 2 rois per block in one dispatch -> dur ~ 2M, visible in rocprof
__global__ __launch_bounds__(256) void probe_main2(const unsigned short* __restrict__ xt,
                                                   const float* __restrict__ rois,
                                                   float* __restrict__ oprobe) {
    __shared__ float lout[C_ * NBIN];
    __shared__ int   goff[NBIN][4];
    __shared__ float gw[NBIN][4];
    #pragma unroll 1
    for (int rep = 0; rep < 2; rep++) {
        int r = (blockIdx.x + rep * 1000) % 2000;
        main_roi(xt, rois, oprobe + (size_t)r * (C_ * NBIN),
                 r, threadIdx.x, lout, goff, gw);
        __syncthreads();
    }
}

// ---------------------------------------------------------------------------
// Fallback (no workspace): direct NCHW gather, thread = channel (f32 exact)
// ---------------------------------------------------------------------------
__global__ __launch_bounds__(256) void rroi_main_direct(const float* __restrict__ x,
                                                        const float* __restrict__ rois,
                                                        float* __restrict__ outp) {
    __shared__ float lout[C_ * NBIN];
    __shared__ int   goff[NBIN][4];
    __shared__ float gw[NBIN][4];

    int r = blockIdx.x;
    int tid = threadIdx.x;

    if (tid < NBIN) {
        int b, yt, yb, xl, xr; float w[4];
        compute_geom(rois, r, tid, b, yt, yb, xl, xr, w);
        int base = b * C_ * HW_;
        goff[tid][0] = base + yt * W_ + xl;
        goff[tid][1] = base + yt * W_ + xr;
        goff[tid][2] = base + yb * W_ + xl;
        goff[tid][3] = base + yb * W_ + xr;
        gw[tid][0] = w[0]; gw[tid][1] = w[1]; gw[tid][2] = w[2]; gw[tid][3] = w[3];
    }
    __syncthreads();

    int c = tid;
    int coff = c * HW_;
    for (int bin = 0; bin < NBIN; bin++) {
        float w0 = gw[bin][0], w1 = gw[bin][1], w2 = gw[bin][2], w3 = gw[bin][3];
        float lt = x[goff[bin][0] + coff];
        float rt = x[goff[bin][1] + coff];
        float lb = x[goff[bin][2] + coff];
        float rb = x[goff[bin][3] + coff];
        float v;
        {
#pragma clang fp contract(off)
            v = ((w0 * lt + w1 * rt) + w3 * rb) + w2 * lb;
        }
        lout[c * NBIN + bin] = v;
    }
    __syncthreads();

    float* o = outp + (size_t)r * (C_ * NBIN);
    const int n4 = (C_ * NBIN) / 4;
    for (int i = tid; i < n4; i += 256)
        *(float4*)(o + i * 4) = *(const float4*)(&lout[i * 4]);
}

// ---------------------------------------------------------------------------
extern "C" void kernel_launch(void* const* d_in, const int* in_sizes, int n_in,
                              void* d_out, int out_size, void* d_ws, size_t ws_size,
                              hipStream_t stream) {
    const float* x    = (const float*)d_in[0];
    const float* rois = (const float*)d_in[1];
    float*       outp = (float*)d_out;
    int R = in_sizes[1] / 6;

    size_t xt_bytes = (size_t)B_ * HW_ * C_ * sizeof(unsigned short);   // 55.7 MB
    if (ws_size >= xt_bytes) {
        unsigned short* xt = (unsigned short*)d_ws;
        dim3 g(HW_ / 64, C_ / 64, B_);       // 850 x 4 x 2 = 6800 blocks
        transpose_bf16<<<g, 256, 0, stream>>>(x, xt);
        rroi_main_bf16<<<R, 256, 0, stream>>>(xt, rois, outp);

        // --- measurement probes (write only to scratch; deterministic) ---
        size_t off_pt = 64ull  * 1024 * 1024;                 // probe xt region
        size_t off_pm = 192ull * 1024 * 1024;                 // probe out region
        size_t need_probe = off_pm + (size_t)2000 * C_ * NBIN * sizeof(float);
        if (ws_size >= need_probe) {
            unsigned short* pxt = (unsigned short*)((char*)d_ws + off_pt);
            float*          pom = (float*)((char*)d_ws + off_pm);
            probe_transpose4<<<6800, 256, 0, stream>>>(x, pxt);
            probe_main2<<<1000, 256, 0, stream>>>(xt, rois, pom);
        }
    } else {
        rroi_main_direct<<<R, 256, 0, stream>>>(x, rois, outp);
    }
}

// Round 7
// 76.985 us; speedup vs baseline: 3.1449x; 3.1449x over previous
//
#include <hip/hip_runtime.h>
#include <math.h>

#define B_   2
#define C_   256
#define H_   200
#define W_   272
#define HW_  (H_*W_)
#define NBIN 49
#define SCALE 0.0625f

// ---------------------------------------------------------------------------
// bf16 helpers (staging buffer only; all arithmetic stays f32)
// ---------------------------------------------------------------------------
__device__ __forceinline__ unsigned short f2bf(float f) {
    union { float f; unsigned int i; } v; v.f = f;
    unsigned int x = v.i;
    return (unsigned short)((x + 0x7FFFu + ((x >> 16) & 1u)) >> 16);   // RNE
}
__device__ __forceinline__ float bf2f(unsigned int u16) {
    union { unsigned int i; float f; } v; v.i = u16 << 16; return v.f;
}

// ---------------------------------------------------------------------------
// Geometry: bit-exact vs numpy f32 reference (verified: absmax 0.0 in R1).
// DO NOT TOUCH: fp contract off, same association order, f64 trig.
// ---------------------------------------------------------------------------
__device__ __forceinline__ float edge_mask(float yy, float xx) {
    return (yy > -1.0f && yy < (float)H_ && xx > -1.0f && xx < (float)W_) ? 1.0f : 0.0f;
}

__device__ void compute_geom(const float* __restrict__ rois, int r, int bin,
                             int& b, int& yt, int& yb, int& xl, int& xr,
                             float w[4]) {
#pragma clang fp contract(off)
    const float* rp = rois + r * 6;
    b = (int)rp[0];
    float cx = rp[1] * SCALE;
    float cy = rp[2] * SCALE;
    float rw = rp[3] * SCALE;
    float rh = rp[4] * SCALE;
    float theta = rp[5] * (float)(M_PI / 180.0);
    float Sx = rw / 7.0f;
    float Sy = rh / 7.0f;
    double th = (double)theta;
    float ca = (float)cos(th);
    float sa = (float)sin(th);

    float M00 = ca * Sx;
    float M01 = sa * Sy;
    float M02 = (M00 * (-3.5f) + M01 * (-3.5f)) + cx;
    float M10 = (-sa) * Sx;
    float M11 = ca * Sy;
    float M12 = (M10 * (-3.5f) + M11 * (-3.5f)) + cy;

    float pwf = (float)(bin % 7);
    float phf = (float)(bin / 7);
    float x0 = pwf, x1 = pwf + 1.0f;
    float y0 = phf, y1 = phf + 1.0f;

    float X00 = (M00 * x0 + M01 * y0) + M02;
    float X01 = (M00 * x0 + M01 * y1) + M02;
    float X10 = (M00 * x1 + M01 * y0) + M02;
    float X11 = (M00 * x1 + M01 * y1) + M02;
    float Y00 = (M10 * x0 + M11 * y0) + M12;
    float Y01 = (M10 * x0 + M11 * y1) + M12;
    float Y10 = (M10 * x1 + M11 * y0) + M12;
    float Y11 = (M10 * x1 + M11 * y1) + M12;

    float minX = fminf(fminf(X00, X01), fminf(X10, X11));
    float maxX = fmaxf(fmaxf(X00, X01), fmaxf(X10, X11));
    float minY = fminf(fminf(Y00, Y01), fminf(Y10, Y11));
    float maxY = fmaxf(fmaxf(Y00, Y01), fmaxf(Y10, Y11));

    float leftMost   = fmaxf(floorf(minX + 0.5f), 0.0f);
    float rightMost  = fminf(floorf(maxX + 0.5f), (float)(W_ - 1));
    float topMost    = fmaxf(floorf(minY + 0.5f), 0.0f);
    float bottomMost = fminf(floorf(maxY + 0.5f), (float)(H_ - 1));

    float bcx = (leftMost + rightMost) * 0.5f;
    float bcy = (topMost + bottomMost) * 0.5f;
    float fl = floorf(bcx), fr = ceilf(bcx);
    float ft = floorf(bcy), fb = ceilf(bcy);
    float rx = bcx - fl;
    float ry = bcy - ft;

    float wlt = (1.0f - rx) * (1.0f - ry);
    float wrt = rx * (1.0f - ry);
    float wrb = rx * ry;
    float wlb = (1.0f - rx) * ry;

    w[0] = wlt * edge_mask(ft, fl);
    w[1] = wrt * edge_mask(ft, fr);
    w[2] = wlb * edge_mask(fb, fl);
    w[3] = wrb * edge_mask(fb, fr);

    yt = min(max((int)ft, 0), H_ - 1);
    yb = min(max((int)fb, 0), H_ - 1);
    xl = min(max((int)fl, 0), W_ - 1);
    xr = min(max((int)fr, 0), W_ - 1);
}

// ---------------------------------------------------------------------------
// Kernel 1: NCHW f32 -> NHWC bf16 transpose (R2-proven 64x64 tile) PLUS a
// 5th blockIdx.y slice that precomputes the per-bin geometry table in ws.
// Geometry's f64 trig hides inside the memory-bound transpose (VALUBusy 10%).
// geom[gid*8]: [0..3] = tap offsets (NHWC elem idx), [4..7] = weights (bits).
// ---------------------------------------------------------------------------
__global__ __launch_bounds__(256) void transpose_geom(const float* __restrict__ in,
                                                      unsigned short* __restrict__ xt,
                                                      unsigned int* __restrict__ geom,
                                                      const float* __restrict__ rois,
                                                      int R) {
    if (blockIdx.y == 4) {
        int total = R * NBIN;
        for (int gid = (blockIdx.z * 850 + blockIdx.x) * 256 + threadIdx.x;
             gid < total; gid += 1700 * 256) {
            int r = gid / NBIN, bin = gid - r * NBIN;
            int b, yt, yb, xl, xr; float w[4];
            compute_geom(rois, r, bin, b, yt, yb, xl, xr, w);
            int base = b * HW_ * C_;
            uint4 o, wu;
            o.x = base + (yt * W_ + xl) * C_;
            o.y = base + (yt * W_ + xr) * C_;
            o.z = base + (yb * W_ + xl) * C_;
            o.w = base + (yb * W_ + xr) * C_;
            wu.x = __float_as_uint(w[0]);
            wu.y = __float_as_uint(w[1]);
            wu.z = __float_as_uint(w[2]);
            wu.w = __float_as_uint(w[3]);
            uint4* gp = (uint4*)(geom + (size_t)gid * 8);
            gp[0] = o;
            gp[1] = wu;
        }
        return;
    }

    __shared__ float tile[64][65];     // 16.6 KB
    int b  = blockIdx.z;
    int p0 = blockIdx.x * 64;          // spatial base
    int c0 = blockIdx.y * 64;          // channel base
    const float*    ib = in + (size_t)b * C_ * HW_;
    unsigned short* ob = xt + (size_t)b * HW_ * C_;
    int t = threadIdx.x;

    {
        int col4 = t & 15;             // which float4 along pixels
        int row  = t >> 4;             // channel row 0..15
        #pragma unroll
        for (int k = 0; k < 4; k++) {
            int c = row + k * 16;
            float4 v = *(const float4*)(ib + (size_t)(c0 + c) * HW_ + p0 + col4 * 4);
            int p = col4 * 4;
            tile[p + 0][c] = v.x;
            tile[p + 1][c] = v.y;
            tile[p + 2][c] = v.z;
            tile[p + 3][c] = v.w;
        }
    }
    __syncthreads();
    {
        int c8 = t & 7;                // which 8-channel group (16 B bf16)
        int pr = t >> 3;               // pixel row 0..31
        #pragma unroll
        for (int k = 0; k < 2; k++) {
            int p = pr + k * 32;
            ushort4 lo, hi;
            const float* tp = &tile[p][c8 * 8];
            lo.x = f2bf(tp[0]); lo.y = f2bf(tp[1]); lo.z = f2bf(tp[2]); lo.w = f2bf(tp[3]);
            hi.x = f2bf(tp[4]); hi.y = f2bf(tp[5]); hi.z = f2bf(tp[6]); hi.w = f2bf(tp[7]);
            unsigned short* dst = ob + (size_t)(p0 + p) * C_ + c0 + c8 * 8;
            *(ushort4*)(dst)     = lo;
            *(ushort4*)(dst + 4) = hi;
        }
    }
}

// ---------------------------------------------------------------------------
// Kernel 2: pure gather/combine. No trig, no geometry barrier. Per wave:
// 32 B uniform geom load (pipelined 1-deep) + 4 x 512 B coalesced tap loads.
// lout staging ([c][bin], swizzled scalar stores) + float4 copy-out: R2-proven.
// ---------------------------------------------------------------------------
__global__ __launch_bounds__(256) void rroi_main_bf16(const unsigned short* __restrict__ xt,
                                                      const unsigned int* __restrict__ geom,
                                                      float* __restrict__ outp) {
    __shared__ float lout[C_ * NBIN];          // 50176 B

    int r    = blockIdx.x;
    int tid  = threadIdx.x;
    int lane = tid & 63;
    int wv   = tid >> 6;
    int c4   = lane * 4;

    const uint4* gb = (const uint4*)(geom + (size_t)r * NBIN * 8);

    int bin = wv;
    uint4 go = gb[2 * bin];
    uint4 gu = gb[2 * bin + 1];
    while (bin < NBIN) {
        int nbin = bin + 4;
        uint4 ngo, ngu;
        if (nbin < NBIN) {                     // prefetch next iter's geom
            ngo = gb[2 * nbin];
            ngu = gb[2 * nbin + 1];
        }
        float w0 = __uint_as_float(gu.x), w1 = __uint_as_float(gu.y);
        float w2 = __uint_as_float(gu.z), w3 = __uint_as_float(gu.w);
        uint2 lt = *(const uint2*)(xt + go.x + c4);
        uint2 rt = *(const uint2*)(xt + go.y + c4);
        uint2 lb = *(const uint2*)(xt + go.z + c4);
        uint2 rb = *(const uint2*)(xt + go.w + c4);
        float acc[4];
        {
#pragma clang fp contract(off)
            float a0 = bf2f(lt.x & 0xFFFFu), a1 = bf2f(lt.x >> 16),
                  a2 = bf2f(lt.y & 0xFFFFu), a3 = bf2f(lt.y >> 16);
            float b0 = bf2f(rt.x & 0xFFFFu), b1 = bf2f(rt.x >> 16),
                  b2 = bf2f(rt.y & 0xFFFFu), b3 = bf2f(rt.y >> 16);
            float c0v = bf2f(lb.x & 0xFFFFu), c1v = bf2f(lb.x >> 16),
                  c2v = bf2f(lb.y & 0xFFFFu), c3v = bf2f(lb.y >> 16);
            float d0 = bf2f(rb.x & 0xFFFFu), d1 = bf2f(rb.x >> 16),
                  d2 = bf2f(rb.y & 0xFFFFu), d3 = bf2f(rb.y >> 16);
            acc[0] = ((w0 * a0 + w1 * b0) + w3 * d0) + w2 * c0v;
            acc[1] = ((w0 * a1 + w1 * b1) + w3 * d1) + w2 * c1v;
            acc[2] = ((w0 * a2 + w1 * b2) + w3 * d2) + w2 * c2v;
            acc[3] = ((w0 * a3 + w1 * b3) + w3 * d3) + w2 * c3v;
        }
        #pragma unroll
        for (int jj = 0; jj < 4; jj++) {
            int j = (jj + (lane >> 3)) & 3;    // swizzle: <=2 lanes/bank
            float v = (j == 0) ? acc[0] : (j == 1) ? acc[1] : (j == 2) ? acc[2] : acc[3];
            lout[(c4 + j) * NBIN + bin] = v;
        }
        go = ngo; gu = ngu; bin = nbin;
    }
    __syncthreads();

    float4*       o4 = (float4*)(outp + (size_t)r * (C_ * NBIN));
    const float4* l4 = (const float4*)lout;
    const int n4 = (C_ * NBIN) / 4;            // 3136
    for (int i = tid; i < n4; i += 256) o4[i] = l4[i];
}

// ---------------------------------------------------------------------------
// Fallback (no workspace): direct NCHW gather, thread = channel (f32 exact)
// ---------------------------------------------------------------------------
__global__ __launch_bounds__(256) void rroi_main_direct(const float* __restrict__ x,
                                                        const float* __restrict__ rois,
                                                        float* __restrict__ outp) {
    __shared__ float lout[C_ * NBIN];
    __shared__ int   goff[NBIN][4];
    __shared__ float gw[NBIN][4];

    int r = blockIdx.x;
    int tid = threadIdx.x;

    if (tid < NBIN) {
        int b, yt, yb, xl, xr; float w[4];
        compute_geom(rois, r, tid, b, yt, yb, xl, xr, w);
        int base = b * C_ * HW_;
        goff[tid][0] = base + yt * W_ + xl;
        goff[tid][1] = base + yt * W_ + xr;
        goff[tid][2] = base + yb * W_ + xl;
        goff[tid][3] = base + yb * W_ + xr;
        gw[tid][0] = w[0]; gw[tid][1] = w[1]; gw[tid][2] = w[2]; gw[tid][3] = w[3];
    }
    __syncthreads();

    int c = tid;
    int coff = c * HW_;
    for (int bin = 0; bin < NBIN; bin++) {
        float w0 = gw[bin][0], w1 = gw[bin][1], w2 = gw[bin][2], w3 = gw[bin][3];
        float lt = x[goff[bin][0] + coff];
        float rt = x[goff[bin][1] + coff];
        float lb = x[goff[bin][2] + coff];
        float rb = x[goff[bin][3] + coff];
        float v;
        {
#pragma clang fp contract(off)
            v = ((w0 * lt + w1 * rt) + w3 * rb) + w2 * lb;
        }
        lout[c * NBIN + bin] = v;
    }
    __syncthreads();

    float* o = outp + (size_t)r * (C_ * NBIN);
    const int n4 = (C_ * NBIN) / 4;
    for (int i = tid; i < n4; i += 256)
        *(float4*)(o + i * 4) = *(const float4*)(&lout[i * 4]);
}

// ---------------------------------------------------------------------------
extern "C" void kernel_launch(void* const* d_in, const int* in_sizes, int n_in,
                              void* d_out, int out_size, void* d_ws, size_t ws_size,
                              hipStream_t stream) {
    const float* x    = (const float*)d_in[0];
    const float* rois = (const float*)d_in[1];
    float*       outp = (float*)d_out;
    int R = in_sizes[1] / 6;

    size_t geom_off = 64ull * 1024 * 1024;                       // after 55.7MB xt
    size_t need = geom_off + (size_t)R * NBIN * 8 * sizeof(unsigned int);
    if (ws_size >= need) {
        unsigned short* xt   = (unsigned short*)d_ws;
        unsigned int*   geom = (unsigned int*)((char*)d_ws + geom_off);
        dim3 g(HW_ / 64, 5, B_);       // y<4: transpose tiles; y==4: geometry
        transpose_geom<<<g, 256, 0, stream>>>(x, xt, geom, rois, R);
        rroi_main_bf16<<<R, 256, 0, stream>>>(xt, geom, outp);
    } else {
        rroi_main_direct<<<R, 256, 0, stream>>>(x, rois, outp);
    }
}